// Round 1
// baseline (445.192 us; speedup 1.0000x reference)
//
#include <hip/hip_runtime.h>
#include <cstdint>
#include <cstddef>

// Dual attention (channel attention), B=16 S=512 D=1024 H=16 dk=64.
// Pipeline:
//   1. pack: f32 -> bf16 splits (hi/lo for q,k,Wq,Wk; hi-only for v,Wv,Wo)
//   2. Pq = split-bf16 GEMM(query,Wq^T)+bq   (3-term: hi*hi + hi*lo + lo*hi, fp32-grade)
//      Pk = same for key; Pv = plain bf16 GEMM(value,Wv^T)+bv   (f32 outputs)
//   3. scores[b,i,j] = 0.25 * sum_{r in batch, c} Pq[r,64i+c]*Pk[r,64j+c]  (f32 vector)
//   4. softmax -> attn (to d_out) ; Mm = I + beta*attn
//   5. xmix[r, 64i+c] = bf16( sum_j Mm[i,j] * Pv[r, 64j+c] )
//   6. out = bf16 GEMM(xmix, Wo^T) + bo  -> d_out
// mask (d_in[3]) and adj (d_in[4]) are unused by the reference.

#define M_ROWS 8192   // B*S
#define DIM 1024

typedef __bf16 bf16_t;
typedef __bf16 bf16x4_t __attribute__((ext_vector_type(4)));
typedef __bf16 bf16x8_t __attribute__((ext_vector_type(8)));
typedef float  f32x4_t  __attribute__((ext_vector_type(4)));

__device__ __forceinline__ void async_ld16(const void* g, void* l) {
    __builtin_amdgcn_global_load_lds((const __attribute__((address_space(1))) void*)g,
                                     (__attribute__((address_space(3))) void*)l,
                                     16, 0, 0);
}

// ---------------------------------------------------------------- pack kernel
// float4 units: q 2097152 | k 2097152 | Wq 262144 | Wk 262144 | v 2097152
//               Wv 262144 | Wo 262144   => total 7340032 units, 28672 blocks
__global__ __launch_bounds__(256) void pack_kernel(
    const float* __restrict__ q, const float* __restrict__ k, const float* __restrict__ v,
    const float* __restrict__ Wq, const float* __restrict__ Wk,
    const float* __restrict__ Wv, const float* __restrict__ Wo,
    bf16_t* __restrict__ AqH, bf16_t* __restrict__ AqL,
    bf16_t* __restrict__ AkH, bf16_t* __restrict__ AkL,
    bf16_t* __restrict__ Av,
    bf16_t* __restrict__ BqH, bf16_t* __restrict__ BqL,
    bf16_t* __restrict__ BkH, bf16_t* __restrict__ BkL,
    bf16_t* __restrict__ Bv, bf16_t* __restrict__ Bo)
{
    const int u = blockIdx.x * 256 + threadIdx.x;

    if (u < 2097152) {
        float4 s = ((const float4*)q)[u];
        bf16x4_t h, l;
        h[0]=(bf16_t)s.x; h[1]=(bf16_t)s.y; h[2]=(bf16_t)s.z; h[3]=(bf16_t)s.w;
        l[0]=(bf16_t)(s.x-(float)h[0]); l[1]=(bf16_t)(s.y-(float)h[1]);
        l[2]=(bf16_t)(s.z-(float)h[2]); l[3]=(bf16_t)(s.w-(float)h[3]);
        ((bf16x4_t*)AqH)[u] = h; ((bf16x4_t*)AqL)[u] = l;
    } else if (u < 4194304) {
        int i = u - 2097152;
        float4 s = ((const float4*)k)[i];
        bf16x4_t h, l;
        h[0]=(bf16_t)s.x; h[1]=(bf16_t)s.y; h[2]=(bf16_t)s.z; h[3]=(bf16_t)s.w;
        l[0]=(bf16_t)(s.x-(float)h[0]); l[1]=(bf16_t)(s.y-(float)h[1]);
        l[2]=(bf16_t)(s.z-(float)h[2]); l[3]=(bf16_t)(s.w-(float)h[3]);
        ((bf16x4_t*)AkH)[i] = h; ((bf16x4_t*)AkL)[i] = l;
    } else if (u < 4456448) {
        int i = u - 4194304;
        float4 s = ((const float4*)Wq)[i];
        bf16x4_t h, l;
        h[0]=(bf16_t)s.x; h[1]=(bf16_t)s.y; h[2]=(bf16_t)s.z; h[3]=(bf16_t)s.w;
        l[0]=(bf16_t)(s.x-(float)h[0]); l[1]=(bf16_t)(s.y-(float)h[1]);
        l[2]=(bf16_t)(s.z-(float)h[2]); l[3]=(bf16_t)(s.w-(float)h[3]);
        ((bf16x4_t*)BqH)[i] = h; ((bf16x4_t*)BqL)[i] = l;
    } else if (u < 4718592) {
        int i = u - 4456448;
        float4 s = ((const float4*)Wk)[i];
        bf16x4_t h, l;
        h[0]=(bf16_t)s.x; h[1]=(bf16_t)s.y; h[2]=(bf16_t)s.z; h[3]=(bf16_t)s.w;
        l[0]=(bf16_t)(s.x-(float)h[0]); l[1]=(bf16_t)(s.y-(float)h[1]);
        l[2]=(bf16_t)(s.z-(float)h[2]); l[3]=(bf16_t)(s.w-(float)h[3]);
        ((bf16x4_t*)BkH)[i] = h; ((bf16x4_t*)BkL)[i] = l;
    } else if (u < 6815744) {
        int i = u - 4718592;
        float4 s = ((const float4*)v)[i];
        bf16x4_t h;
        h[0]=(bf16_t)s.x; h[1]=(bf16_t)s.y; h[2]=(bf16_t)s.z; h[3]=(bf16_t)s.w;
        ((bf16x4_t*)Av)[i] = h;
    } else if (u < 7077888) {
        int i = u - 6815744;
        float4 s = ((const float4*)Wv)[i];
        bf16x4_t h;
        h[0]=(bf16_t)s.x; h[1]=(bf16_t)s.y; h[2]=(bf16_t)s.z; h[3]=(bf16_t)s.w;
        ((bf16x4_t*)Bv)[i] = h;
    } else {
        int i = u - 7077888;
        float4 s = ((const float4*)Wo)[i];
        bf16x4_t h;
        h[0]=(bf16_t)s.x; h[1]=(bf16_t)s.y; h[2]=(bf16_t)s.z; h[3]=(bf16_t)s.w;
        ((bf16x4_t*)Bo)[i] = h;
    }
}

// ---------------------------------------------------------------- GEMM
// C[m,n] = sum_k A[m,k]*B[n,k] + bias[n]; A row-major [8192,1024], B row-major
// [1024,1024] (i.e. W [out,in], so C = A @ W^T). three=1: 3-term split
// accumulation (Ahi*Bhi + Ahi*Blo + Alo*Bhi). Tile 128x128, BK=64, 4 waves.
__global__ __launch_bounds__(256) void gemm_bt(
    const bf16_t* __restrict__ Ahi, const bf16_t* __restrict__ Alo,
    const bf16_t* __restrict__ Bhi, const bf16_t* __restrict__ Blo,
    const float* __restrict__ bias, float* __restrict__ C, int three)
{
    __shared__ __align__(16) bf16_t As[128 * 64];
    __shared__ __align__(16) bf16_t Bs[128 * 64];

    const int tid  = threadIdx.x;
    const int lane = tid & 63;
    const int w    = tid >> 6;
    const int tileM = blockIdx.x * 128;
    const int tileN = blockIdx.y * 128;
    const int wm = (w & 1) << 6;
    const int wn = (w >> 1) << 6;

    f32x4_t acc[4][4];
#pragma unroll
    for (int i = 0; i < 4; ++i)
#pragma unroll
        for (int j = 0; j < 4; ++j)
            acc[i][j] = (f32x4_t){0.f, 0.f, 0.f, 0.f};

    const int srow = lane >> 3;          // staging: row within 8-row chunk
    const int scol = (lane & 7) << 3;    // staging: bf16 col (8 elems = 16 B)
    const int arow = lane & 15;          // mfma frag row/col
    const int kq   = (lane >> 4) << 3;   // mfma frag k-offset

    const int ktiles = three ? 48 : 16;
    for (int kt = 0; kt < ktiles; ++kt) {
        const int term = kt >> 4;
        const int k0 = (kt & 15) << 6;
        const bf16_t* Asrc = (term == 2) ? Alo : Ahi;
        const bf16_t* Bsrc = (term == 1) ? Blo : Bhi;
#pragma unroll
        for (int t = 0; t < 4; ++t) {
            const int row = (w << 5) + (t << 3);  // wave-uniform chunk base
            async_ld16(Asrc + (size_t)(tileM + row + srow) * DIM + k0 + scol,
                       (void*)(As + row * 64));
            async_ld16(Bsrc + (size_t)(tileN + row + srow) * DIM + k0 + scol,
                       (void*)(Bs + row * 64));
        }
        __syncthreads();
#pragma unroll
        for (int kk = 0; kk < 64; kk += 32) {
            bf16x8_t af[4], bfv[4];
#pragma unroll
            for (int mt = 0; mt < 4; ++mt)
                af[mt] = *(const bf16x8_t*)(As + (wm + (mt << 4) + arow) * 64 + kk + kq);
#pragma unroll
            for (int nt = 0; nt < 4; ++nt)
                bfv[nt] = *(const bf16x8_t*)(Bs + (wn + (nt << 4) + arow) * 64 + kk + kq);
#pragma unroll
            for (int mt = 0; mt < 4; ++mt)
#pragma unroll
                for (int nt = 0; nt < 4; ++nt)
                    acc[mt][nt] = __builtin_amdgcn_mfma_f32_16x16x32_bf16(
                        af[mt], bfv[nt], acc[mt][nt], 0, 0, 0);
        }
        __syncthreads();
    }

    // C/D layout: col = lane&15, row = (lane>>4)*4 + reg
    const int rq = (lane >> 4) << 2;
#pragma unroll
    for (int nt = 0; nt < 4; ++nt) {
        const int col = tileN + wn + (nt << 4) + arow;
        const float bv = bias[col];
#pragma unroll
        for (int mt = 0; mt < 4; ++mt) {
            const int row = tileM + wm + (mt << 4) + rq;
#pragma unroll
            for (int r = 0; r < 4; ++r)
                C[(size_t)(row + r) * DIM + col] = acc[mt][nt][r] + bv;
        }
    }
}

// ---------------------------------------------------------------- scores
// grid (16 batches, 8 row-chunks of 64). lane = c (0..63), wave w owns 4 j's.
__global__ __launch_bounds__(256) void scores_kernel(
    const float* __restrict__ Pq, const float* __restrict__ Pk,
    float* __restrict__ scores)
{
    const int b = blockIdx.x;
    const int chunk = blockIdx.y;
    const int lane = threadIdx.x & 63;
    const int w = threadIdx.x >> 6;

    float acc[16][4];
#pragma unroll
    for (int i = 0; i < 16; ++i)
#pragma unroll
        for (int jj = 0; jj < 4; ++jj) acc[i][jj] = 0.f;

    const int r0 = b * 512 + chunk * 64;
    for (int rr = 0; rr < 64; ++rr) {
        const float* qrow = Pq + (size_t)(r0 + rr) * DIM;
        const float* krow = Pk + (size_t)(r0 + rr) * DIM;
        float kv[4];
#pragma unroll
        for (int jj = 0; jj < 4; ++jj)
            kv[jj] = krow[(w * 4 + jj) * 64 + lane];
#pragma unroll
        for (int i = 0; i < 16; ++i) {
            float qv = qrow[i * 64 + lane];
#pragma unroll
            for (int jj = 0; jj < 4; ++jj) acc[i][jj] += qv * kv[jj];
        }
    }
#pragma unroll
    for (int i = 0; i < 16; ++i)
#pragma unroll
        for (int jj = 0; jj < 4; ++jj) {
            float v2 = acc[i][jj];
            for (int off = 32; off; off >>= 1) v2 += __shfl_down(v2, off);
            if (lane == 0)
                atomicAdd(&scores[b * 256 + i * 16 + w * 4 + jj], v2);
        }
}

// ---------------------------------------------------------------- softmax
// 1 block, 256 threads: thread t = (b,i) row; attn -> d_out; Mm = I + beta*attn
__global__ __launch_bounds__(256) void softmax_kernel(
    const float* __restrict__ scores, const float* __restrict__ beta_p,
    float* __restrict__ attn_out, float* __restrict__ Mm)
{
    const int t = threadIdx.x;
    const int i = t & 15;
    const float beta = beta_p[0];
    float s[16];
    float mx = -1e30f;
#pragma unroll
    for (int j = 0; j < 16; ++j) {
        s[j] = scores[t * 16 + j] * 0.25f;   // 1/sqrt(h), h=16
        mx = fmaxf(mx, s[j]);
    }
    float sum = 0.f;
#pragma unroll
    for (int j = 0; j < 16; ++j) { s[j] = expf(s[j] - mx); sum += s[j]; }
    const float inv = 1.f / sum;
#pragma unroll
    for (int j = 0; j < 16; ++j) {
        float a = s[j] * inv;
        attn_out[t * 16 + j] = a;
        Mm[t * 16 + j] = beta * a + ((j == i) ? 1.f : 0.f);
    }
}

// ---------------------------------------------------------------- channel mix
// xmix[r, 64i+c] = bf16( sum_j Mm[b,i,j] * Pv[r, 64j+c] ). 512 blocks x 16 rows.
__global__ __launch_bounds__(256) void mix_kernel(
    const float* __restrict__ Pv, const float* __restrict__ Mm,
    bf16_t* __restrict__ xmix)
{
    __shared__ float Msh[256];
    const int rbase = blockIdx.x * 16;
    const int b = rbase >> 9;
    Msh[threadIdx.x] = Mm[b * 256 + threadIdx.x];
    __syncthreads();
    const int w = threadIdx.x >> 6;
    const int lane = threadIdx.x & 63;
    for (int rr = 0; rr < 4; ++rr) {
        const int r = rbase + w * 4 + rr;
        const float* vrow = Pv + (size_t)r * DIM;
        float v[16];
#pragma unroll
        for (int j = 0; j < 16; ++j) v[j] = vrow[j * 64 + lane];
#pragma unroll
        for (int i = 0; i < 16; ++i) {
            float x = 0.f;
#pragma unroll
            for (int j = 0; j < 16; ++j) x += Msh[i * 16 + j] * v[j];
            xmix[(size_t)r * DIM + i * 64 + lane] = (bf16_t)x;
        }
    }
}

// ---------------------------------------------------------------- launch
extern "C" void kernel_launch(void* const* d_in, const int* in_sizes, int n_in,
                              void* d_out, int out_size, void* d_ws, size_t ws_size,
                              hipStream_t stream)
{
    (void)in_sizes; (void)n_in; (void)out_size; (void)ws_size;
    const float* q    = (const float*)d_in[0];
    const float* k    = (const float*)d_in[1];
    const float* v    = (const float*)d_in[2];
    // d_in[3] mask, d_in[4] adj: unused by reference
    const float* Wq   = (const float*)d_in[5];
    const float* bq   = (const float*)d_in[6];
    const float* Wk   = (const float*)d_in[7];
    const float* bk   = (const float*)d_in[8];
    const float* Wv   = (const float*)d_in[9];
    const float* bv   = (const float*)d_in[10];
    const float* Wo   = (const float*)d_in[11];
    const float* bo   = (const float*)d_in[12];
    const float* beta = (const float*)d_in[13];

    float* out  = (float*)d_out;                     // [8192,1024]
    float* attn = (float*)d_out + 8388608;           // [16,16,16]

    char* p = (char*)d_ws;
    auto take = [&](size_t n) -> char* {
        char* cur = p; p += (n + 255) & ~(size_t)255; return cur;
    };
    bf16_t* AqH = (bf16_t*)take(16777216);
    bf16_t* AqL = (bf16_t*)take(16777216);
    bf16_t* AkH = (bf16_t*)take(16777216);
    bf16_t* AkL = (bf16_t*)take(16777216);
    bf16_t* Av  = (bf16_t*)take(16777216);
    bf16_t* BqH = (bf16_t*)take(2097152);
    bf16_t* BqL = (bf16_t*)take(2097152);
    bf16_t* BkH = (bf16_t*)take(2097152);
    bf16_t* BkL = (bf16_t*)take(2097152);
    bf16_t* Bv  = (bf16_t*)take(2097152);
    bf16_t* Bo  = (bf16_t*)take(2097152);
    float*  Pq  = (float*)take(33554432);
    float*  Pk  = (float*)take(33554432);
    float*  Pv  = (float*)take(33554432);
    float*  scores = (float*)take(16384);
    float*  Mm     = (float*)take(16384);
    bf16_t* xmix = AqH;  // AqH dead after Pq GEMM; reuse for xmix

    pack_kernel<<<28672, 256, 0, stream>>>(q, k, v, Wq, Wk, Wv, Wo,
                                           AqH, AqL, AkH, AkL, Av,
                                           BqH, BqL, BkH, BkL, Bv, Bo);
    hipMemsetAsync(scores, 0, 16384, stream);

    dim3 ggrid(64, 8);
    gemm_bt<<<ggrid, 256, 0, stream>>>(AqH, AqL, BqH, BqL, bq, Pq, 1);
    gemm_bt<<<ggrid, 256, 0, stream>>>(AkH, AkL, BkH, BkL, bk, Pk, 1);
    gemm_bt<<<ggrid, 256, 0, stream>>>(Av,  Av,  Bv,  Bv,  bv, Pv, 0);

    scores_kernel<<<dim3(16, 8), 256, 0, stream>>>(Pq, Pk, scores);
    softmax_kernel<<<1, 256, 0, stream>>>(scores, beta, attn, Mm);
    mix_kernel<<<512, 256, 0, stream>>>(Pv, Mm, xmix);
    gemm_bt<<<ggrid, 256, 0, stream>>>(xmix, xmix, Bo, Bo, bo, out, 0);
}

// Round 2
// 338.828 us; speedup vs baseline: 1.3139x; 1.3139x over previous
//
#include <hip/hip_runtime.h>
#include <cstdint>
#include <cstddef>

// Dual attention (channel attention), B=16 S=512 D=1024 H=16 dk=64.
// Round 2: fp16 single-pass GEMMs (fp16 rel err 1.4e-4 -> score err ~0.009,
// attn err ~0.01 < ~0.031 threshold) + XOR-swizzled LDS layout to kill the
// 16-lane/4-bank ds_read_b128 conflicts seen in round 1 (1.9e7 cycles/disp).
// Pipeline:
//   1. pack: f32 -> fp16 (q,k,v,Wq,Wk,Wv,Wo)
//   2. Pq,Pk,Pv = fp16 MFMA GEMM (A @ W^T + b), f32 outputs
//   3. scores[b,i,j] = 0.25 * sum_{s,c} Pq[b,s,64i+c]*Pk[b,s,64j+c]
//   4. softmax -> attn (d_out tail); Mm = I + beta*attn
//   5. xmix[r,64i+c] = f16( sum_j Mm[i,j]*Pv[r,64j+c] )
//   6. out = f16 GEMM(xmix, Wo^T) + bo -> d_out
// mask (d_in[3]) and adj (d_in[4]) are unused by the reference.

#define DIM 1024

typedef _Float16 f16_t;
typedef _Float16 f16x4_t __attribute__((ext_vector_type(4)));
typedef _Float16 f16x8_t __attribute__((ext_vector_type(8)));
typedef float    f32x4_t __attribute__((ext_vector_type(4)));

__device__ __forceinline__ void async_ld16(const void* g, void* l) {
    __builtin_amdgcn_global_load_lds((const __attribute__((address_space(1))) void*)g,
                                     (__attribute__((address_space(3))) void*)l,
                                     16, 0, 0);
}

// ---------------------------------------------------------------- pack kernel
// float4 units: q 2097152 | k 2097152 | v 2097152 | Wq 262144 | Wk 262144
//               | Wv 262144 | Wo 262144 => 7340032 units, 28672 blocks
__global__ __launch_bounds__(256) void pack_kernel(
    const float* __restrict__ q, const float* __restrict__ k, const float* __restrict__ v,
    const float* __restrict__ Wq, const float* __restrict__ Wk,
    const float* __restrict__ Wv, const float* __restrict__ Wo,
    f16_t* __restrict__ Aq, f16_t* __restrict__ Ak, f16_t* __restrict__ Av,
    f16_t* __restrict__ Bq, f16_t* __restrict__ Bk,
    f16_t* __restrict__ Bv, f16_t* __restrict__ Bo)
{
    const int u = blockIdx.x * 256 + threadIdx.x;
    const float* src; f16_t* dst; int i;
    if (u < 2097152)      { src = q;  dst = Aq; i = u; }
    else if (u < 4194304) { src = k;  dst = Ak; i = u - 2097152; }
    else if (u < 6291456) { src = v;  dst = Av; i = u - 4194304; }
    else if (u < 6553600) { src = Wq; dst = Bq; i = u - 6291456; }
    else if (u < 6815744) { src = Wk; dst = Bk; i = u - 6553600; }
    else if (u < 7077888) { src = Wv; dst = Bv; i = u - 6815744; }
    else                  { src = Wo; dst = Bo; i = u - 7077888; }
    float4 s = ((const float4*)src)[i];
    f16x4_t h;
    h[0] = (f16_t)s.x; h[1] = (f16_t)s.y; h[2] = (f16_t)s.z; h[3] = (f16_t)s.w;
    ((f16x4_t*)dst)[i] = h;
}

// ---------------------------------------------------------------- GEMM
// C[m,n] = sum_k A[m,k]*B[n,k] + bias[n]. A [8192,1024] f16 row-major,
// B [1024,1024] f16 row-major (W [out,in] -> C = A@W^T). Tile 128x128, BK=64,
// 4 waves. LDS layout XOR-swizzled: LDS(row, cu) = global(row, cu ^ (row&7))
// in 16B column units, so 16-lane fragment reads spread across all 32 banks
// (2-way aliasing only, which is free).
__global__ __launch_bounds__(256) void gemm_f16(
    const f16_t* __restrict__ A, const f16_t* __restrict__ B,
    const float* __restrict__ bias, float* __restrict__ C)
{
    __shared__ __align__(16) f16_t As[128 * 64];
    __shared__ __align__(16) f16_t Bs[128 * 64];

    const int tid  = threadIdx.x;
    const int lane = tid & 63;
    const int w    = tid >> 6;
    const int tileM = blockIdx.x * 128;
    const int tileN = blockIdx.y * 128;
    const int wm = (w & 1) << 6;
    const int wn = (w >> 1) << 6;

    f32x4_t acc[4][4];
#pragma unroll
    for (int i = 0; i < 4; ++i)
#pragma unroll
        for (int j = 0; j < 4; ++j)
            acc[i][j] = (f32x4_t){0.f, 0.f, 0.f, 0.f};

    const int srow = lane >> 3;                      // staging row in 8-row chunk
    const int scol = ((lane & 7) ^ (lane >> 3)) << 3; // swizzled fetch col (elems)
    const int arow = lane & 15;                      // mfma frag row/col
    const int sx   = lane & 7;                       // reader swizzle (= row&7)
    const int kqu  = lane >> 4;                      // frag k 16B-unit (0..3)

    for (int kt = 0; kt < 16; ++kt) {
        const int k0 = kt << 6;
#pragma unroll
        for (int t = 0; t < 4; ++t) {
            const int row = (w << 5) + (t << 3);     // wave-uniform chunk base
            async_ld16(A + (size_t)(tileM + row + srow) * DIM + k0 + scol,
                       (void*)(As + row * 64));
            async_ld16(B + (size_t)(tileN + row + srow) * DIM + k0 + scol,
                       (void*)(Bs + row * 64));
        }
        __syncthreads();
#pragma unroll
        for (int kk = 0; kk < 2; ++kk) {             // two 16B-unit groups: u=kk*4+kqu
            const int cu = ((kk << 2) + kqu) ^ sx;   // swizzled LDS column unit
            f16x8_t af[4], bfv[4];
#pragma unroll
            for (int mt = 0; mt < 4; ++mt)
                af[mt] = *(const f16x8_t*)(As + (wm + (mt << 4) + arow) * 64 + (cu << 3));
#pragma unroll
            for (int nt = 0; nt < 4; ++nt)
                bfv[nt] = *(const f16x8_t*)(Bs + (wn + (nt << 4) + arow) * 64 + (cu << 3));
#pragma unroll
            for (int mt = 0; mt < 4; ++mt)
#pragma unroll
                for (int nt = 0; nt < 4; ++nt)
                    acc[mt][nt] = __builtin_amdgcn_mfma_f32_16x16x32_f16(
                        af[mt], bfv[nt], acc[mt][nt], 0, 0, 0);
        }
        __syncthreads();
    }

    // C/D layout: col = lane&15, row = (lane>>4)*4 + reg
    const int rq = (lane >> 4) << 2;
#pragma unroll
    for (int nt = 0; nt < 4; ++nt) {
        const int col = tileN + wn + (nt << 4) + arow;
        const float bv = bias[col];
#pragma unroll
        for (int mt = 0; mt < 4; ++mt) {
            const int row = tileM + wm + (mt << 4) + rq;
#pragma unroll
            for (int r = 0; r < 4; ++r)
                C[(size_t)(row + r) * DIM + col] = acc[mt][nt][r] + bv;
        }
    }
}

// ---------------------------------------------------------------- scores
// grid (16 batches, 32 row-chunks of 16). lane = c (0..63), wave w owns 4 j's.
__global__ __launch_bounds__(256) void scores_kernel(
    const float* __restrict__ Pq, const float* __restrict__ Pk,
    float* __restrict__ scores)
{
    const int b = blockIdx.x;
    const int chunk = blockIdx.y;
    const int lane = threadIdx.x & 63;
    const int w = threadIdx.x >> 6;

    float acc[16][4];
#pragma unroll
    for (int i = 0; i < 16; ++i)
#pragma unroll
        for (int jj = 0; jj < 4; ++jj) acc[i][jj] = 0.f;

    const int r0 = b * 512 + chunk * 16;
    for (int rr = 0; rr < 16; ++rr) {
        const float* qrow = Pq + (size_t)(r0 + rr) * DIM;
        const float* krow = Pk + (size_t)(r0 + rr) * DIM;
        float kv[4];
#pragma unroll
        for (int jj = 0; jj < 4; ++jj)
            kv[jj] = krow[(w * 4 + jj) * 64 + lane];
#pragma unroll
        for (int i = 0; i < 16; ++i) {
            float qv = qrow[i * 64 + lane];
#pragma unroll
            for (int jj = 0; jj < 4; ++jj) acc[i][jj] += qv * kv[jj];
        }
    }
#pragma unroll
    for (int i = 0; i < 16; ++i)
#pragma unroll
        for (int jj = 0; jj < 4; ++jj) {
            float v2 = acc[i][jj];
            for (int off = 32; off; off >>= 1) v2 += __shfl_down(v2, off);
            if (lane == 0)
                atomicAdd(&scores[b * 256 + i * 16 + w * 4 + jj], v2);
        }
}

// ---------------------------------------------------------------- softmax
// 1 block, 256 threads: thread t = (b,i) row; attn -> d_out tail; Mm = I + beta*attn
__global__ __launch_bounds__(256) void softmax_kernel(
    const float* __restrict__ scores, const float* __restrict__ beta_p,
    float* __restrict__ attn_out, float* __restrict__ Mm)
{
    const int t = threadIdx.x;
    const int i = t & 15;
    const float beta = beta_p[0];
    float s[16];
    float mx = -1e30f;
#pragma unroll
    for (int j = 0; j < 16; ++j) {
        s[j] = scores[t * 16 + j] * 0.25f;   // 1/sqrt(h), h=16
        mx = fmaxf(mx, s[j]);
    }
    float sum = 0.f;
#pragma unroll
    for (int j = 0; j < 16; ++j) { s[j] = expf(s[j] - mx); sum += s[j]; }
    const float inv = 1.f / sum;
#pragma unroll
    for (int j = 0; j < 16; ++j) {
        float a = s[j] * inv;
        attn_out[t * 16 + j] = a;
        Mm[t * 16 + j] = beta * a + ((j == i) ? 1.f : 0.f);
    }
}

// ---------------------------------------------------------------- channel mix
// xmix[r,64i+c] = f16( sum_j Mm[b,i,j] * Pv[r,64j+c] ). 512 blocks x 16 rows.
__global__ __launch_bounds__(256) void mix_kernel(
    const float* __restrict__ Pv, const float* __restrict__ Mm,
    f16_t* __restrict__ xmix)
{
    __shared__ float Msh[256];
    const int rbase = blockIdx.x * 16;
    const int b = rbase >> 9;
    Msh[threadIdx.x] = Mm[b * 256 + threadIdx.x];
    __syncthreads();
    const int w = threadIdx.x >> 6;
    const int lane = threadIdx.x & 63;
    for (int rr = 0; rr < 4; ++rr) {
        const int r = rbase + w * 4 + rr;
        const float* vrow = Pv + (size_t)r * DIM;
        float v[16];
#pragma unroll
        for (int j = 0; j < 16; ++j) v[j] = vrow[j * 64 + lane];
#pragma unroll
        for (int i = 0; i < 16; ++i) {
            float x = 0.f;
#pragma unroll
            for (int j = 0; j < 16; ++j) x += Msh[i * 16 + j] * v[j];
            xmix[(size_t)r * DIM + i * 64 + lane] = (f16_t)x;
        }
    }
}

// ---------------------------------------------------------------- launch
extern "C" void kernel_launch(void* const* d_in, const int* in_sizes, int n_in,
                              void* d_out, int out_size, void* d_ws, size_t ws_size,
                              hipStream_t stream)
{
    (void)in_sizes; (void)n_in; (void)out_size; (void)ws_size;
    const float* q    = (const float*)d_in[0];
    const float* k    = (const float*)d_in[1];
    const float* v    = (const float*)d_in[2];
    // d_in[3] mask, d_in[4] adj: unused by reference
    const float* Wq   = (const float*)d_in[5];
    const float* bq   = (const float*)d_in[6];
    const float* Wk   = (const float*)d_in[7];
    const float* bk   = (const float*)d_in[8];
    const float* Wv   = (const float*)d_in[9];
    const float* bv   = (const float*)d_in[10];
    const float* Wo   = (const float*)d_in[11];
    const float* bo   = (const float*)d_in[12];
    const float* beta = (const float*)d_in[13];

    float* out  = (float*)d_out;                     // [8192,1024]
    float* attn = (float*)d_out + 8388608;           // [16,16,16]

    char* p = (char*)d_ws;
    auto take = [&](size_t n) -> char* {
        char* cur = p; p += (n + 255) & ~(size_t)255; return cur;
    };
    f16_t* Aq = (f16_t*)take(16777216);
    f16_t* Ak = (f16_t*)take(16777216);
    f16_t* Av = (f16_t*)take(16777216);
    f16_t* Bq = (f16_t*)take(2097152);
    f16_t* Bk = (f16_t*)take(2097152);
    f16_t* Bv = (f16_t*)take(2097152);
    f16_t* Bo = (f16_t*)take(2097152);
    float* Pq = (float*)take(33554432);
    float* Pk = (float*)take(33554432);
    float* Pv = (float*)take(33554432);
    float* scores = (float*)take(16384);
    float* Mm     = (float*)take(16384);
    f16_t* xmix = Aq;  // Aq dead after Pq GEMM; reuse for xmix

    pack_kernel<<<28672, 256, 0, stream>>>(q, k, v, Wq, Wk, Wv, Wo,
                                           Aq, Ak, Av, Bq, Bk, Bv, Bo);
    hipMemsetAsync(scores, 0, 16384, stream);

    dim3 ggrid(64, 8);
    gemm_f16<<<ggrid, 256, 0, stream>>>(Aq, Bq, bq, Pq);
    gemm_f16<<<ggrid, 256, 0, stream>>>(Ak, Bk, bk, Pk);
    gemm_f16<<<ggrid, 256, 0, stream>>>(Av, Bv, bv, Pv);

    scores_kernel<<<dim3(16, 32), 256, 0, stream>>>(Pq, Pk, scores);
    softmax_kernel<<<1, 256, 0, stream>>>(scores, beta, attn, Mm);
    mix_kernel<<<512, 256, 0, stream>>>(Pv, Mm, xmix);
    gemm_f16<<<ggrid, 256, 0, stream>>>(xmix, Bo, bo, out);
}